// Round 1
// baseline (960.374 us; speedup 1.0000x reference)
//
#include <hip/hip_runtime.h>

// K-Sparse Autoencoder fwd: B=4096, D=768, H=16384, K=32 (constants fixed by reference)
constexpr int NB = 4096;
constexpr int ND = 768;
constexpr int NH = 16384;
constexpr int NK = 32;
constexpr int CAND_MAX = 256;
#define DELTA 0.10f   // safety margin over bf16-vs-f32 encode error (~25 sigma)

typedef __bf16 bf16x8 __attribute__((ext_vector_type(8)));
typedef float  f32x4  __attribute__((ext_vector_type(4)));

// ---------------- workspace layout (bytes) ----------------
constexpr size_t OFF_XBF   = 0;                                  // x in bf16        [NB][ND]
constexpr size_t OFF_WENCB = OFF_XBF   + (size_t)NB * ND * 2;    // W_enc in bf16    [NH][ND]
constexpr size_t OFF_WDECT = OFF_WENCB + (size_t)NH * ND * 2;    // W_dec transposed [NH][ND] f32
constexpr size_t OFF_CIDX  = OFF_WDECT + (size_t)NH * ND * 4;    // cand_idx [NB][CAND_MAX]
constexpr size_t OFF_CCNT  = OFF_CIDX  + (size_t)NB * CAND_MAX * 4; // cand_cnt [NB]
constexpr size_t OFF_SIDX  = OFF_CCNT  + (size_t)NB * 4;         // sel_idx [NB][NK]
constexpr size_t OFF_SVAL  = OFF_SIDX  + (size_t)NB * NK * 4;    // sel_val [NB][NK]

__device__ inline unsigned short f2bf(float f) {
  unsigned u = __float_as_uint(f);
  unsigned r = u + 0x7fffu + ((u >> 16) & 1u);   // RNE (no NaN in this data)
  return (unsigned short)(r >> 16);
}

// ---------------- K1: f32 -> bf16 cast (vectorized) ----------------
__global__ __launch_bounds__(256) void cast_bf16_kernel(const float* __restrict__ in,
                                                        unsigned short* __restrict__ out,
                                                        int n4) {
  int stride = gridDim.x * 256;
  for (int i = blockIdx.x * 256 + threadIdx.x; i < n4; i += stride) {
    float4 v = ((const float4*)in)[i];
    unsigned long long p = (unsigned long long)f2bf(v.x)
                         | ((unsigned long long)f2bf(v.y) << 16)
                         | ((unsigned long long)f2bf(v.z) << 32)
                         | ((unsigned long long)f2bf(v.w) << 48);
    ((unsigned long long*)out)[i] = p;
  }
}

// ---------------- K2: transpose W_dec [ND][NH] -> [NH][ND] ----------------
__global__ __launch_bounds__(256) void transpose_kernel(const float* __restrict__ in,
                                                        float* __restrict__ out) {
  __shared__ float tile[32][33];                  // +1 pad: no bank conflicts
  int hb = blockIdx.x * 32, db = blockIdx.y * 32;
  int tx = threadIdx.x, ty = threadIdx.y;         // 32 x 8
#pragma unroll
  for (int i = 0; i < 4; ++i) {
    int d = db + ty + i * 8;
    tile[ty + i * 8][tx] = in[(size_t)d * NH + hb + tx];
  }
  __syncthreads();
#pragma unroll
  for (int i = 0; i < 4; ++i) {
    int h = hb + ty + i * 8;
    out[(size_t)h * ND + db + tx] = tile[tx][ty + i * 8];
  }
}

// ---------------- K3: approx encode GEMM, bf16 MFMA ----------------
// za = relu(x_bf16 @ W_enc_bf16^T + b_enc)  -> f32 into zout [NB][NH]
// 128x128 tile, BK=64, 4 waves (2x2), each wave 4x4 frags of 16x16x32.
__global__ __launch_bounds__(256) void encode_gemm_kernel(
    const unsigned short* __restrict__ Abf,   // [NB][ND]
    const unsigned short* __restrict__ Bbf,   // [NH][ND]
    const float* __restrict__ b_enc,
    float* __restrict__ zout) {
  __shared__ __align__(16) unsigned short As[128 * 64];
  __shared__ __align__(16) unsigned short Bs[128 * 64];

  int bid = blockIdx.x;
  int swz = (bid & 7) * 512 + (bid >> 3);   // XCD-aware swizzle, 4096 % 8 == 0
  int bm = swz & 31;                        // NB/128 = 32
  int bn = swz >> 5;                        // NH/128 = 128
  int m0 = bm * 128, n0 = bn * 128;

  int tid = threadIdx.x;
  int wid = tid >> 6, l = tid & 63;
  int wr = wid >> 1, wc = wid & 1;
  int lr = l & 15;        // row within 16x16 frag
  int lk = l >> 4;        // k-group 0..3

  f32x4 acc[4][4] = {};

  const int4* gA = (const int4*)Abf;   // ND/8 = 96 int4 per row
  const int4* gB = (const int4*)Bbf;

  for (int kt = 0; kt < 12; ++kt) {    // ND/64
    int4 ar[4], br[4];
#pragma unroll
    for (int i = 0; i < 4; ++i) {
      int c = tid + 256 * i;
      int row = c >> 3, kc = c & 7;
      ar[i] = gA[(size_t)(m0 + row) * 96 + kt * 8 + kc];
      br[i] = gB[(size_t)(n0 + row) * 96 + kt * 8 + kc];
    }
    __syncthreads();                   // prior tile's ds_reads done
#pragma unroll
    for (int i = 0; i < 4; ++i) {
      int c = tid + 256 * i;
      *(int4*)&As[c * 8] = ar[i];
      *(int4*)&Bs[c * 8] = br[i];
    }
    __syncthreads();
#pragma unroll
    for (int kk = 0; kk < 2; ++kk) {
      bf16x8 af[4], bq[4];
#pragma unroll
      for (int i = 0; i < 4; ++i) {
        int4 t = *(const int4*)&As[(wr * 64 + i * 16 + lr) * 64 + kk * 32 + lk * 8];
        af[i] = __builtin_bit_cast(bf16x8, t);
      }
#pragma unroll
      for (int j = 0; j < 4; ++j) {
        int4 t = *(const int4*)&Bs[(wc * 64 + j * 16 + lr) * 64 + kk * 32 + lk * 8];
        bq[j] = __builtin_bit_cast(bf16x8, t);
      }
#pragma unroll
      for (int i = 0; i < 4; ++i)
#pragma unroll
        for (int j = 0; j < 4; ++j)
          acc[i][j] = __builtin_amdgcn_mfma_f32_16x16x32_bf16(af[i], bq[j], acc[i][j], 0, 0, 0);
    }
  }

  // epilogue: bias + relu, C/D layout col=l&15, row=(l>>4)*4+q  [verified mapping]
#pragma unroll
  for (int j = 0; j < 4; ++j) {
    int n = n0 + wc * 64 + j * 16 + lr;
    float bias = b_enc[n];
#pragma unroll
    for (int i = 0; i < 4; ++i) {
      int mbase = m0 + wr * 64 + i * 16 + lk * 4;
#pragma unroll
      for (int q = 0; q < 4; ++q)
        zout[(size_t)(mbase + q) * NH + n] = fmaxf(acc[i][j][q] + bias, 0.0f);
    }
  }
}

// ---------------- K4: per-row rank-32 threshold (bit-bisection) + candidates ----------------
__global__ __launch_bounds__(256) void select_kernel(const float* __restrict__ zout,
                                                     int* __restrict__ cand_idx,
                                                     int* __restrict__ cand_cnt) {
  int b = blockIdx.x, tid = threadIdx.x;
  const float4* zrow = (const float4*)(zout + (size_t)b * NH);
  float4 v[16];
#pragma unroll
  for (int i = 0; i < 16; ++i) v[i] = zrow[tid + 256 * i];

  __shared__ unsigned wcnt[4];
  __shared__ unsigned go_hi;
  __shared__ int lcnt;

  unsigned lo = 0u, hi = 0x7f800000u;    // za >= 0 -> float bits are order-preserving
  for (int it = 0; it < 24; ++it) {
    unsigned mid = (lo + hi) >> 1;
    int c = 0;
#pragma unroll
    for (int i = 0; i < 16; ++i) {
      const float* vp = (const float*)&v[i];
#pragma unroll
      for (int e = 0; e < 4; ++e) c += (__float_as_uint(vp[e]) >= mid) ? 1 : 0;
    }
#pragma unroll
    for (int off = 32; off; off >>= 1) c += __shfl_xor(c, off, 64);
    if ((tid & 63) == 0) wcnt[tid >> 6] = (unsigned)c;
    __syncthreads();
    if (tid == 0) {
      unsigned tot = wcnt[0] + wcnt[1] + wcnt[2] + wcnt[3];
      go_hi = (tot >= 32u) ? 1u : 0u;
    }
    __syncthreads();
    if (go_hi) lo = mid; else hi = mid;
  }
  // invariant: count(za >= lo) >= 32. Candidates: za >= lo - DELTA (covers bf16 error).
  float thr = __uint_as_float(lo) - DELTA;
  if (thr < 1e-12f) thr = 1e-12f;        // rows with <32 positives: positives only
  if (tid == 0) lcnt = 0;
  __syncthreads();
#pragma unroll
  for (int i = 0; i < 16; ++i) {
    const float* vp = (const float*)&v[i];
#pragma unroll
    for (int e = 0; e < 4; ++e) {
      if (vp[e] >= thr) {
        int h = 4 * (tid + 256 * i) + e;
        int slot = atomicAdd(&lcnt, 1);
        if (slot < CAND_MAX) cand_idx[(size_t)b * CAND_MAX + slot] = h;
      }
    }
  }
  __syncthreads();
  if (tid == 0) cand_cnt[b] = (lcnt < CAND_MAX) ? lcnt : CAND_MAX;
}

// ---------------- K5: exact f32 recompute of candidates, top-32, write final z row ----------------
__global__ __launch_bounds__(256) void recompute_kernel(
    const float* __restrict__ x, const float* __restrict__ W_enc,
    const float* __restrict__ b_enc,
    const int* __restrict__ cand_idx, const int* __restrict__ cand_cnt,
    float* __restrict__ zout,
    int* __restrict__ sel_idx, float* __restrict__ sel_val) {
  int b = blockIdx.x, tid = threadIdx.x;
  int wid = tid >> 6, l = tid & 63;
  __shared__ __align__(16) float xr[ND];
  __shared__ float cv[CAND_MAX];
  __shared__ int   ci[CAND_MAX];
  __shared__ float sv[NK];
  __shared__ int   si[NK];

  int cnt = cand_cnt[b];
  {
    const float4* xrow = (const float4*)(x + (size_t)b * ND);
    for (int i = tid; i < ND / 4; i += 256) ((float4*)xr)[i] = xrow[i];
    for (int c = tid; c < cnt; c += 256) ci[c] = cand_idx[(size_t)b * CAND_MAX + c];
  }
  __syncthreads();

  // one wave per candidate, exact f32 dot (matches reference within ~1e-6)
  for (int c = wid; c < cnt; c += 4) {
    int h = ci[c];
    const float* wrow = W_enc + (size_t)h * ND;
    float s = 0.f;
#pragma unroll
    for (int i = 0; i < 12; ++i) s = fmaf(wrow[l + 64 * i], xr[l + 64 * i], s);
#pragma unroll
    for (int off = 32; off; off >>= 1) s += __shfl_xor(s, off, 64);
    if (l == 0) cv[c] = fmaxf(s + b_enc[h], 0.f);
  }
  __syncthreads();

  // wave 0: deterministic top-32 by (value desc, index asc) — jax.lax.top_k tie-break
  if (wid == 0) {
    float lv[4]; int lh[4];
#pragma unroll
    for (int ii = 0; ii < 4; ++ii) {
      int c = l + 64 * ii;
      if (c < cnt) { lv[ii] = cv[c]; lh[ii] = ci[c]; }
      else         { lv[ii] = -1.f;  lh[ii] = 0x7fffffff; }
    }
    for (int r = 0; r < NK; ++r) {
      float bv = -1.f; int bh = 0x7fffffff; int bl = l; int bii = 0;
#pragma unroll
      for (int ii = 0; ii < 4; ++ii)
        if (lv[ii] > bv || (lv[ii] == bv && lh[ii] < bh)) { bv = lv[ii]; bh = lh[ii]; bii = ii; }
#pragma unroll
      for (int off = 32; off; off >>= 1) {
        float ov = __shfl_xor(bv, off, 64);
        int   oh = __shfl_xor(bh, off, 64);
        int   ol = __shfl_xor(bl, off, 64);
        int   oi = __shfl_xor(bii, off, 64);
        if (ov > bv || (ov == bv && oh < bh)) { bv = ov; bh = oh; bl = ol; bii = oi; }
      }
      if (l == 0) {
        if (bv > -0.5f) { sv[r] = bv; si[r] = bh; }
        else            { sv[r] = 0.f; si[r] = 0; }   // <32 candidates: pad (contributes 0)
      }
#pragma unroll
      for (int ii = 0; ii < 4; ++ii)
        if (ii == bii && l == bl && bv > -0.5f) lv[ii] = -1.f;  // retire winner (register-only)
    }
  }
  __syncthreads();

  // final z row: zeros everywhere, then scatter exact top-32
  float4 z4 = make_float4(0.f, 0.f, 0.f, 0.f);
  float4* zr = (float4*)(zout + (size_t)b * NH);
  for (int i = tid; i < NH / 4; i += 256) zr[i] = z4;
  __syncthreads();
  if (tid < NK) {
    zout[(size_t)b * NH + si[tid]] = sv[tid];
    sel_idx[b * NK + tid] = si[tid];
    sel_val[b * NK + tid] = sv[tid];
  }
}

// ---------------- K6: sparse decode x_hat = b_dec + sum_j v_j * W_decT[h_j,:] ----------------
__global__ __launch_bounds__(256) void decode_kernel(
    const float* __restrict__ WdecT,   // [NH][ND]
    const float* __restrict__ b_dec,
    const int* __restrict__ sel_idx, const float* __restrict__ sel_val,
    float* __restrict__ xhat) {
  int b = blockIdx.x, tid = threadIdx.x;
  __shared__ int   si[NK];
  __shared__ float sv[NK];
  if (tid < NK) { si[tid] = sel_idx[b * NK + tid]; sv[tid] = sel_val[b * NK + tid]; }
  __syncthreads();
  float a0 = b_dec[tid], a1 = b_dec[tid + 256], a2 = b_dec[tid + 512];
#pragma unroll 8
  for (int j = 0; j < NK; ++j) {
    const float* wrow = WdecT + (size_t)si[j] * ND;
    float vj = sv[j];
    a0 = fmaf(vj, wrow[tid],       a0);
    a1 = fmaf(vj, wrow[tid + 256], a1);
    a2 = fmaf(vj, wrow[tid + 512], a2);
  }
  xhat[(size_t)b * ND + tid]       = a0;
  xhat[(size_t)b * ND + tid + 256] = a1;
  xhat[(size_t)b * ND + tid + 512] = a2;
}

// ---------------- launcher ----------------
extern "C" void kernel_launch(void* const* d_in, const int* in_sizes, int n_in,
                              void* d_out, int out_size, void* d_ws, size_t ws_size,
                              hipStream_t stream) {
  const float* x     = (const float*)d_in[0];
  const float* W_enc = (const float*)d_in[1];
  const float* b_enc = (const float*)d_in[2];
  const float* W_dec = (const float*)d_in[3];
  const float* b_dec = (const float*)d_in[4];
  // d_in[5] is k (device scalar); fixed at 32 by the problem constants.

  float* xhat = (float*)d_out;
  float* zout = (float*)d_out + (size_t)NB * ND;   // z region doubles as za scratch

  char* ws = (char*)d_ws;
  unsigned short* x_bf    = (unsigned short*)(ws + OFF_XBF);
  unsigned short* wenc_bf = (unsigned short*)(ws + OFF_WENCB);
  float*          wdecT   = (float*)(ws + OFF_WDECT);
  int*            cidx    = (int*)(ws + OFF_CIDX);
  int*            ccnt    = (int*)(ws + OFF_CCNT);
  int*            sidx    = (int*)(ws + OFF_SIDX);
  float*          sval    = (float*)(ws + OFF_SVAL);

  cast_bf16_kernel<<<1024, 256, 0, stream>>>(x, x_bf, NB * ND / 4);
  cast_bf16_kernel<<<2048, 256, 0, stream>>>(W_enc, wenc_bf, NH * ND / 4);
  transpose_kernel<<<dim3(NH / 32, ND / 32), dim3(32, 8), 0, stream>>>(W_dec, wdecT);
  encode_gemm_kernel<<<(NB / 128) * (NH / 128), 256, 0, stream>>>(x_bf, wenc_bf, b_enc, zout);
  select_kernel<<<NB, 256, 0, stream>>>(zout, cidx, ccnt);
  recompute_kernel<<<NB, 256, 0, stream>>>(x, W_enc, b_enc, cidx, ccnt, zout, sidx, sval);
  decode_kernel<<<NB, 256, 0, stream>>>(wdecT, b_dec, sidx, sval, xhat);
}

// Round 3
// 830.613 us; speedup vs baseline: 1.1562x; 1.1562x over previous
//
#include <hip/hip_runtime.h>

// K-Sparse Autoencoder fwd: B=4096, D=768, H=16384, K=32
// Determinism notes (tripwire discipline):
//  - no cross-call state: every ws/d_out byte read within a call is written earlier in that call
//  - candidate SET is deterministic (full bisection, CAND_MAX=512 >> worst-case ~90)
//  - top-32 is order-independent (total order on (value desc, index asc)); padding uses si=-1
//  - all LDS write->read hand-offs are separated by __syncthreads() (full LDS fence)
constexpr int NB = 4096;
constexpr int ND = 768;
constexpr int NH = 16384;
constexpr int NK = 32;
constexpr int CAND_MAX = 512;
#define DELTA 0.10f   // bf16-MFMA accum err + bf16 za quantization <= ~0.015 worst; 6x margin

typedef __bf16 bf16x8 __attribute__((ext_vector_type(8)));
typedef float  f32x4  __attribute__((ext_vector_type(4)));

// ---------------- workspace layout (bytes) ----------------
constexpr size_t OFF_XBF   = 0;                                     // x bf16      [NB][ND]
constexpr size_t OFF_WENCB = OFF_XBF   + (size_t)NB * ND * 2;       // W_enc bf16  [NH][ND]
constexpr size_t OFF_WDECT = OFF_WENCB + (size_t)NH * ND * 2;       // W_dec^T f32 [NH][ND]
constexpr size_t OFF_CIDX  = OFF_WDECT + (size_t)NH * ND * 4;       // cand_idx [NB][CAND_MAX]
constexpr size_t OFF_CCNT  = OFF_CIDX  + (size_t)NB * CAND_MAX * 4; // cand_cnt [NB]
// total ~90 MB (round-1 proved >=87 MB fits)

__device__ inline unsigned short f2bf(float f) {
  unsigned u = __float_as_uint(f);
  unsigned r = u + 0x7fffu + ((u >> 16) & 1u);   // RNE
  return (unsigned short)(r >> 16);
}

// ---------------- K1: f32 -> bf16 cast ----------------
__global__ __launch_bounds__(256) void cast_bf16_kernel(const float* __restrict__ in,
                                                        unsigned short* __restrict__ out,
                                                        int n4) {
  int stride = gridDim.x * 256;
  for (int i = blockIdx.x * 256 + threadIdx.x; i < n4; i += stride) {
    float4 v = ((const float4*)in)[i];
    unsigned long long p = (unsigned long long)f2bf(v.x)
                         | ((unsigned long long)f2bf(v.y) << 16)
                         | ((unsigned long long)f2bf(v.z) << 32)
                         | ((unsigned long long)f2bf(v.w) << 48);
    ((unsigned long long*)out)[i] = p;
  }
}

// ---------------- K2: transpose W_dec [ND][NH] -> [NH][ND] f32 ----------------
__global__ __launch_bounds__(256) void transpose_kernel(const float* __restrict__ in,
                                                        float* __restrict__ out) {
  __shared__ float tile[32][33];
  int hb = blockIdx.x * 32, db = blockIdx.y * 32;
  int tx = threadIdx.x, ty = threadIdx.y;   // 32 x 8
#pragma unroll
  for (int i = 0; i < 4; ++i)
    tile[ty + i * 8][tx] = in[(size_t)(db + ty + i * 8) * NH + hb + tx];
  __syncthreads();
#pragma unroll
  for (int i = 0; i < 4; ++i)
    out[(size_t)(hb + ty + i * 8) * ND + db + tx] = tile[tx][ty + i * 8];
}

// ---------------- K3: encode GEMM (bf16 MFMA) -> za bf16 ----------------
// Round-1-proven reg-staged 2-barrier structure; NEW: XOR bank-swizzle on both explicit
// LDS sides (write+read), bf16 epilogue staged through LDS with explicit fences.
__global__ __launch_bounds__(256) void encode_gemm_kernel(
    const unsigned short* __restrict__ Abf,   // [NB][ND]
    const unsigned short* __restrict__ Bbf,   // [NH][ND]
    const float* __restrict__ b_enc,
    unsigned short* __restrict__ za) {        // [NB][NH] bf16
  __shared__ __align__(16) unsigned short As[128 * 64];   // 16 KB
  __shared__ __align__(16) unsigned short Bs[128 * 64];   // 16 KB

  int bid = blockIdx.x;
  int swz = (bid & 7) * 512 + (bid >> 3);   // XCD swizzle, 4096 = 8*512 (bijective)
  int m0 = (swz & 31) * 128;                // NB/128 = 32
  int n0 = (swz >> 5) * 128;                // NH/128 = 128

  int tid = threadIdx.x, wid = tid >> 6, l = tid & 63;
  int wr = wid >> 1, wc = wid & 1;
  int lr = l & 15, lk = l >> 4;

  f32x4 acc[4][4] = {};

  const int4* gA = (const int4*)Abf;   // ND/8 = 96 int4 per row
  const int4* gB = (const int4*)Bbf;

  for (int kt = 0; kt < 12; ++kt) {    // ND/64
    int4 ar[4], br[4];
#pragma unroll
    for (int i = 0; i < 4; ++i) {
      int c = tid + 256 * i;
      int row = c >> 3, unit = c & 7;
      ar[i] = gA[(size_t)(m0 + row) * 96 + kt * 8 + unit];
      br[i] = gB[(size_t)(n0 + row) * 96 + kt * 8 + unit];
    }
    __syncthreads();                   // prior tile's ds_reads done before overwrite
#pragma unroll
    for (int i = 0; i < 4; ++i) {
      int c = tid + 256 * i;
      int row = c >> 3;
      int u = (c & 7) ^ (row & 7);     // bank swizzle (16B units)
      *(int4*)&As[row * 64 + u * 8] = ar[i];
      *(int4*)&Bs[row * 64 + u * 8] = br[i];
    }
    __syncthreads();                   // tile resident
#pragma unroll
    for (int kk = 0; kk < 2; ++kk) {
      bf16x8 af[4], bq[4];
      int u = (kk * 4 + lk) ^ (lr & 7);          // row&7 == lr&7 for all frag rows
#pragma unroll
      for (int i = 0; i < 4; ++i)
        af[i] = *(const bf16x8*)&As[(wr * 64 + i * 16 + lr) * 64 + u * 8];
#pragma unroll
      for (int j = 0; j < 4; ++j)
        bq[j] = *(const bf16x8*)&Bs[(wc * 64 + j * 16 + lr) * 64 + u * 8];
#pragma unroll
      for (int i = 0; i < 4; ++i)
#pragma unroll
        for (int j = 0; j < 4; ++j)
          acc[i][j] = __builtin_amdgcn_mfma_f32_16x16x32_bf16(af[i], bq[j], acc[i][j], 0, 0, 0);
    }
  }

  // ---- epilogue: bias+relu -> bf16, stage via LDS, coalesced 16B stores ----
  __syncthreads();                     // all MFMA ds_reads done; safe to reuse As/Bs
  unsigned short* ep = (wid < 2) ? &As[wid * 4096] : &Bs[(wid - 2) * 4096]; // [64][64]/wave
#pragma unroll
  for (int j = 0; j < 4; ++j) {
    float bias = b_enc[n0 + wc * 64 + j * 16 + lr];
#pragma unroll
    for (int i = 0; i < 4; ++i) {
#pragma unroll
      for (int q = 0; q < 4; ++q) {
        int row = i * 16 + lk * 4 + q;  // local m (C/D: row=(l>>4)*4+q)
        int col = j * 16 + lr;          // local n (col=l&15)
        float v = fmaxf(acc[i][j][q] + bias, 0.0f);
        ep[row * 64 + (((col >> 3) ^ (row & 7)) * 8) + (col & 7)] = f2bf(v);
      }
    }
  }
  __syncthreads();                     // FENCE: LDS writes visible before readback
#pragma unroll
  for (int t = 0; t < 8; ++t) {
    int row = t * 8 + (l >> 3);
    int u = (l & 7) ^ (row & 7);
    int4 d = *(const int4*)&ep[row * 64 + u * 8];
    *(int4*)(za + (size_t)(m0 + wr * 64 + row) * NH + n0 + wc * 64 + (l & 7) * 8) = d;
  }
}

// ---------------- K4: per-row rank-32 threshold (full bf16 bisection) + candidates ----------------
__global__ __launch_bounds__(256) void select_kernel(const unsigned short* __restrict__ za,
                                                     int* __restrict__ cand_idx,
                                                     int* __restrict__ cand_cnt) {
  int b = blockIdx.x, tid = threadIdx.x;
  const uint4* zrow = (const uint4*)(za + (size_t)b * NH);
  uint4 v[8];
#pragma unroll
  for (int i = 0; i < 8; ++i) v[i] = zrow[tid + 256 * i];

  __shared__ int wcnt[4];
  __shared__ int lcnt;

  unsigned lo = 0u, hi = 0x7F80u;   // bf16 bits; za >= 0 -> order-preserving
  for (int it = 0; it < 15; ++it) { // full resolution: lo = exact 32nd-largest bf16 value
    unsigned mid = (lo + hi) >> 1;
    int c = 0;
#pragma unroll
    for (int i = 0; i < 8; ++i) {
      const unsigned* p = (const unsigned*)&v[i];
#pragma unroll
      for (int e = 0; e < 4; ++e) {
        unsigned u = p[e];
        c += ((u & 0xFFFFu) >= mid) ? 1 : 0;
        c += ((u >> 16) >= mid) ? 1 : 0;
      }
    }
#pragma unroll
    for (int off = 32; off; off >>= 1) c += __shfl_xor(c, off, 64);
    if ((tid & 63) == 0) wcnt[tid >> 6] = c;
    __syncthreads();
    int tot = wcnt[0] + wcnt[1] + wcnt[2] + wcnt[3];
    __syncthreads();
    if (tot >= NK) lo = mid; else hi = mid;
  }

  float thr = __uint_as_float(lo << 16) - DELTA;
  if (thr < 1e-12f) thr = 1e-12f;   // degenerate rows: strict positives only
  if (tid == 0) lcnt = 0;
  __syncthreads();
#pragma unroll
  for (int i = 0; i < 8; ++i) {
    const unsigned* p = (const unsigned*)&v[i];
#pragma unroll
    for (int e = 0; e < 4; ++e) {
      unsigned u = p[e];
      int hbase = (tid + 256 * i) * 8 + e * 2;
      float f0 = __uint_as_float((u & 0xFFFFu) << 16);
      float f1 = __uint_as_float(u & 0xFFFF0000u);
      if (f0 >= thr) { int s = atomicAdd(&lcnt, 1); if (s < CAND_MAX) cand_idx[(size_t)b * CAND_MAX + s] = hbase; }
      if (f1 >= thr) { int s = atomicAdd(&lcnt, 1); if (s < CAND_MAX) cand_idx[(size_t)b * CAND_MAX + s] = hbase + 1; }
    }
  }
  __syncthreads();
  if (tid == 0) cand_cnt[b] = (lcnt < CAND_MAX) ? lcnt : CAND_MAX;
}

// ---------------- K5: exact recompute + top-32 + z write + sparse decode (fused) ----------------
__global__ __launch_bounds__(256) void finalize_kernel(
    const float* __restrict__ x, const float* __restrict__ W_enc,
    const float* __restrict__ b_enc,
    const int* __restrict__ cand_idx, const int* __restrict__ cand_cnt,
    const float* __restrict__ WdecT, const float* __restrict__ b_dec,
    float* __restrict__ zout, float* __restrict__ xhat) {
  int b = blockIdx.x, tid = threadIdx.x;
  int wid = tid >> 6, l = tid & 63;
  __shared__ __align__(16) float xr[ND];
  __shared__ float cv[CAND_MAX];
  __shared__ int   ci[CAND_MAX];
  __shared__ float sv[NK];
  __shared__ int   si[NK];

  int cnt = cand_cnt[b];
  {
    const float4* xrow = (const float4*)(x + (size_t)b * ND);
    for (int i = tid; i < ND / 4; i += 256) ((float4*)xr)[i] = xrow[i];
    for (int c = tid; c < cnt; c += 256) ci[c] = cand_idx[(size_t)b * CAND_MAX + c];
  }
  __syncthreads();

  // exact f32 dot per candidate (one wave each) — value depends only on h: order-independent
  for (int c = wid; c < cnt; c += 4) {
    int h = ci[c];
    const float* wrow = W_enc + (size_t)h * ND;
    float s = 0.f;
#pragma unroll
    for (int i = 0; i < 12; ++i) s = fmaf(wrow[l + 64 * i], xr[l + 64 * i], s);
#pragma unroll
    for (int off = 32; off; off >>= 1) s += __shfl_xor(s, off, 64);
    if (l == 0) cv[c] = fmaxf(s + b_enc[h], 0.f);
  }
  __syncthreads();

  // wave 0: deterministic top-32 by (value desc, index asc) — total order, set-deterministic
  if (wid == 0) {
    float lv[8]; int lh[8];
#pragma unroll
    for (int ii = 0; ii < 8; ++ii) {
      int c = l + 64 * ii;
      if (c < cnt) { lv[ii] = cv[c]; lh[ii] = ci[c]; }
      else         { lv[ii] = -1.f;  lh[ii] = 0x7fffffff; }
    }
    for (int r = 0; r < NK; ++r) {
      float bv = -1.f; int bh = 0x7fffffff; int bl = l; int bii = 0;
#pragma unroll
      for (int ii = 0; ii < 8; ++ii)
        if (lv[ii] > bv || (lv[ii] == bv && lh[ii] < bh)) { bv = lv[ii]; bh = lh[ii]; bii = ii; }
#pragma unroll
      for (int off = 32; off; off >>= 1) {
        float ov = __shfl_xor(bv, off, 64);
        int   oh = __shfl_xor(bh, off, 64);
        int   ol = __shfl_xor(bl, off, 64);
        int   oi = __shfl_xor(bii, off, 64);
        if (ov > bv || (ov == bv && oh < bh)) { bv = ov; bh = oh; bl = ol; bii = oi; }
      }
      if (l == 0) {
        if (bv > -0.5f) { sv[r] = bv; si[r] = bh; }
        else            { sv[r] = 0.f; si[r] = -1; }   // sentinel: no write collision
      }
#pragma unroll
      for (int ii = 0; ii < 8; ++ii)
        if (ii == bii && l == bl && bv > -0.5f) lv[ii] = -1.f;  // retire winner
    }
  }
  __syncthreads();

  // z row: zero-fill f32, scatter exact top-32 (guarded: padding never writes)
  float4 z4 = make_float4(0.f, 0.f, 0.f, 0.f);
  float4* zr = (float4*)(zout + (size_t)b * NH);
  for (int i = tid; i < NH / 4; i += 256) zr[i] = z4;
  __syncthreads();
  if (tid < NK) {
    int s = si[tid];
    if (s >= 0) zout[(size_t)b * NH + s] = sv[tid];
  }

  // sparse decode: xhat[b,:] = b_dec + sum_j sv[j] * WdecT[si[j],:]  (sv=0 for padding)
  float a0 = b_dec[tid], a1 = b_dec[tid + 256], a2 = b_dec[tid + 512];
#pragma unroll 8
  for (int j = 0; j < NK; ++j) {
    int hj = si[j]; hj = (hj < 0) ? 0 : hj;
    const float* wrow = WdecT + (size_t)hj * ND;
    float vj = sv[j];
    a0 = fmaf(vj, wrow[tid],       a0);
    a1 = fmaf(vj, wrow[tid + 256], a1);
    a2 = fmaf(vj, wrow[tid + 512], a2);
  }
  xhat[(size_t)b * ND + tid]       = a0;
  xhat[(size_t)b * ND + tid + 256] = a1;
  xhat[(size_t)b * ND + tid + 512] = a2;
}

// ---------------- launcher ----------------
extern "C" void kernel_launch(void* const* d_in, const int* in_sizes, int n_in,
                              void* d_out, int out_size, void* d_ws, size_t ws_size,
                              hipStream_t stream) {
  const float* x     = (const float*)d_in[0];
  const float* W_enc = (const float*)d_in[1];
  const float* b_enc = (const float*)d_in[2];
  const float* W_dec = (const float*)d_in[3];
  const float* b_dec = (const float*)d_in[4];

  float* xhat = (float*)d_out;
  float* zout = (float*)d_out + (size_t)NB * ND;       // final z (f32)
  unsigned short* za = (unsigned short*)zout;          // approx z (bf16) reuses z region

  char* ws = (char*)d_ws;
  unsigned short* x_bf    = (unsigned short*)(ws + OFF_XBF);
  unsigned short* wenc_bf = (unsigned short*)(ws + OFF_WENCB);
  float*          wdecT   = (float*)(ws + OFF_WDECT);
  int*            cidx    = (int*)(ws + OFF_CIDX);
  int*            ccnt    = (int*)(ws + OFF_CCNT);

  cast_bf16_kernel<<<1024, 256, 0, stream>>>(x, x_bf, NB * ND / 4);
  cast_bf16_kernel<<<2048, 256, 0, stream>>>(W_enc, wenc_bf, NH * ND / 4);
  transpose_kernel<<<dim3(NH / 32, ND / 32), dim3(32, 8), 0, stream>>>(W_dec, wdecT);
  encode_gemm_kernel<<<(NB / 128) * (NH / 128), 256, 0, stream>>>(x_bf, wenc_bf, b_enc, za);
  select_kernel<<<NB, 256, 0, stream>>>(za, cidx, ccnt);
  finalize_kernel<<<NB, 256, 0, stream>>>(x, W_enc, b_enc, cidx, ccnt, wdecT, b_dec, zout, xhat);
}

// Round 4
// 476.028 us; speedup vs baseline: 2.0175x; 1.7449x over previous
//
#include <hip/hip_runtime.h>

// K-Sparse Autoencoder fwd: B=4096, D=768, H=16384, K=32
// Determinism notes (tripwire discipline):
//  - no cross-call state: every ws/d_out byte read within a call is written earlier in that call
//  - candidate SET is deterministic (full bisection, CAND_MAX=512 >> worst-case ~90)
//  - top-32 is order-independent (total order on (value desc, index asc)); padding uses si=-1
//  - all LDS write->read hand-offs are separated by __syncthreads() (full LDS fence)
constexpr int NB = 4096;
constexpr int ND = 768;
constexpr int NH = 16384;
constexpr int NK = 32;
constexpr int CAND_MAX = 512;
#define DELTA 0.10f   // bf16-MFMA accum err + bf16 za quantization <= ~0.015 worst; 6x margin

typedef __bf16 bf16x8 __attribute__((ext_vector_type(8)));
typedef float  f32x4  __attribute__((ext_vector_type(4)));

// ---------------- workspace layout (bytes) ----------------
constexpr size_t OFF_XBF   = 0;                                     // x bf16      [NB][ND]
constexpr size_t OFF_WENCB = OFF_XBF   + (size_t)NB * ND * 2;       // W_enc bf16  [NH][ND]
constexpr size_t OFF_WDECT = OFF_WENCB + (size_t)NH * ND * 2;       // W_dec^T f32 [NH][ND]
constexpr size_t OFF_CIDX  = OFF_WDECT + (size_t)NH * ND * 4;       // cand_idx [NB][CAND_MAX]
constexpr size_t OFF_CCNT  = OFF_CIDX  + (size_t)NB * CAND_MAX * 4; // cand_cnt [NB]

__device__ inline unsigned short f2bf(float f) {
  unsigned u = __float_as_uint(f);
  unsigned r = u + 0x7fffu + ((u >> 16) & 1u);   // RNE
  return (unsigned short)(r >> 16);
}

__device__ __forceinline__ void gld_lds16(const unsigned short* g, unsigned short* s) {
  // async global->LDS, 16B/lane; LDS dest = wave-uniform base + lane*16 (HW rule)
  __builtin_amdgcn_global_load_lds((const __attribute__((address_space(1))) void*)g,
                                   (__attribute__((address_space(3))) void*)s, 16, 0, 0);
}

// ---------------- K1: f32 -> bf16 cast ----------------
__global__ __launch_bounds__(256) void cast_bf16_kernel(const float* __restrict__ in,
                                                        unsigned short* __restrict__ out,
                                                        int n4) {
  int stride = gridDim.x * 256;
  for (int i = blockIdx.x * 256 + threadIdx.x; i < n4; i += stride) {
    float4 v = ((const float4*)in)[i];
    unsigned long long p = (unsigned long long)f2bf(v.x)
                         | ((unsigned long long)f2bf(v.y) << 16)
                         | ((unsigned long long)f2bf(v.z) << 32)
                         | ((unsigned long long)f2bf(v.w) << 48);
    ((unsigned long long*)out)[i] = p;
  }
}

// ---------------- K2: transpose W_dec [ND][NH] -> [NH][ND] f32 ----------------
__global__ __launch_bounds__(256) void transpose_kernel(const float* __restrict__ in,
                                                        float* __restrict__ out) {
  __shared__ float tile[32][33];
  int hb = blockIdx.x * 32, db = blockIdx.y * 32;
  int tx = threadIdx.x, ty = threadIdx.y;   // 32 x 8
#pragma unroll
  for (int i = 0; i < 4; ++i)
    tile[ty + i * 8][tx] = in[(size_t)(db + ty + i * 8) * NH + hb + tx];
  __syncthreads();
#pragma unroll
  for (int i = 0; i < 4; ++i)
    out[(size_t)(hb + ty + i * 8) * ND + db + tx] = tile[tx][ty + i * 8];
}

// ---------------- K3: encode GEMM (bf16 MFMA) -> za bf16 ----------------
// Round-3 MFMA loop + epilogue (tripwire-proven) with two changes:
//  (a) super-tile block ordering: per XCD, 8bm x 8bn chunks -> A+B slices (3.2 MB) L2-resident
//  (b) global_load_lds width-16 staging (linear LDS dest + pre-swizzled global source, rule #21)
__global__ __launch_bounds__(256) void encode_gemm_kernel(
    const unsigned short* __restrict__ Abf,   // [NB][ND]
    const unsigned short* __restrict__ Bbf,   // [NH][ND]
    const float* __restrict__ b_enc,
    unsigned short* __restrict__ za) {        // [NB][NH] bf16
  __shared__ __align__(16) unsigned short As[128 * 64];   // 16 KB
  __shared__ __align__(16) unsigned short Bs[128 * 64];   // 16 KB

  // super-tile mapping (bijective): xcd = bid&7 (round-robin heuristic), 64 blocks/super-tile
  int bid = blockIdx.x;                 // 0..4095
  int x  = bid & 7;                     // XCD
  int j  = bid >> 3;                    // 0..511 within XCD
  int st = j >> 6;                      // 0..7: super-tile slot for this XCD
  int w  = j & 63;                      // 0..63 within super-tile
  int g  = st * 8 + x;                  // global super-tile 0..63 (4 sm x 16 sn)
  int bm = (g & 3) * 8 + (w & 7);       // 0..31
  int bn = (g >> 2) * 8 + (w >> 3);     // 0..127
  int m0 = bm * 128, n0 = bn * 128;

  int tid = threadIdx.x, wid = tid >> 6, l = tid & 63;
  int wr = wid >> 1, wc = wid & 1;
  int lr = l & 15, lk = l >> 4;

  // staging source pre-swizzle: lane l lands at LDS row 8c+(l>>3), phys unit (l&7);
  // phys unit u holds logical unit u^(row&7)  =>  fetch logical unit (l&7)^(l>>3)
  int srow = l >> 3;
  int scol = (l & 7) ^ srow;

  f32x4 acc[4][4] = {};

  for (int kt = 0; kt < 12; ++kt) {     // ND/64
    __syncthreads();                    // prior tile's ds_reads done before overwrite
#pragma unroll
    for (int t = 0; t < 4; ++t) {
      int c = wid * 4 + t;              // 16 chunks x 8 rows = 128 rows
      gld_lds16(Abf + ((size_t)(m0 + c * 8 + srow) * ND + kt * 64 + scol * 8), &As[c * 512]);
      gld_lds16(Bbf + ((size_t)(n0 + c * 8 + srow) * ND + kt * 64 + scol * 8), &Bs[c * 512]);
    }
    asm volatile("s_waitcnt vmcnt(0)" ::: "memory");   // belt-and-braces (barrier also drains)
    __syncthreads();                    // tiles resident
#pragma unroll
    for (int kk = 0; kk < 2; ++kk) {
      bf16x8 af[4], bq[4];
      int u = (kk * 4 + lk) ^ (lr & 7);          // swizzled 16B unit (row&7 == lr&7)
#pragma unroll
      for (int i = 0; i < 4; ++i)
        af[i] = *(const bf16x8*)&As[(wr * 64 + i * 16 + lr) * 64 + u * 8];
#pragma unroll
      for (int j2 = 0; j2 < 4; ++j2)
        bq[j2] = *(const bf16x8*)&Bs[(wc * 64 + j2 * 16 + lr) * 64 + u * 8];
#pragma unroll
      for (int i = 0; i < 4; ++i)
#pragma unroll
        for (int j2 = 0; j2 < 4; ++j2)
          acc[i][j2] = __builtin_amdgcn_mfma_f32_16x16x32_bf16(af[i], bq[j2], acc[i][j2], 0, 0, 0);
    }
  }

  // ---- epilogue: bias+relu -> bf16, stage via LDS, coalesced 16B stores (round-3 proven) ----
  __syncthreads();                     // all MFMA ds_reads done; safe to reuse As/Bs
  unsigned short* ep = (wid < 2) ? &As[wid * 4096] : &Bs[(wid - 2) * 4096]; // [64][64]/wave
#pragma unroll
  for (int j2 = 0; j2 < 4; ++j2) {
    float bias = b_enc[n0 + wc * 64 + j2 * 16 + lr];
#pragma unroll
    for (int i = 0; i < 4; ++i) {
#pragma unroll
      for (int q = 0; q < 4; ++q) {
        int row = i * 16 + lk * 4 + q;  // local m (C/D: row=(l>>4)*4+q)
        int col = j2 * 16 + lr;         // local n (col=l&15)
        float v = fmaxf(acc[i][j2][q] + bias, 0.0f);
        ep[row * 64 + (((col >> 3) ^ (row & 7)) * 8) + (col & 7)] = f2bf(v);
      }
    }
  }
  __syncthreads();                     // FENCE: LDS writes visible before readback
#pragma unroll
  for (int t = 0; t < 8; ++t) {
    int row = t * 8 + (l >> 3);
    int u = (l & 7) ^ (row & 7);
    int4 d = *(const int4*)&ep[row * 64 + u * 8];
    *(int4*)(za + (size_t)(m0 + wr * 64 + row) * NH + n0 + wc * 64 + (l & 7) * 8) = d;
  }
}

// ---------------- K4: per-row rank-32 threshold (full bf16 bisection) + candidates ----------------
__global__ __launch_bounds__(256) void select_kernel(const unsigned short* __restrict__ za,
                                                     int* __restrict__ cand_idx,
                                                     int* __restrict__ cand_cnt) {
  int b = blockIdx.x, tid = threadIdx.x;
  const uint4* zrow = (const uint4*)(za + (size_t)b * NH);
  uint4 v[8];
#pragma unroll
  for (int i = 0; i < 8; ++i) v[i] = zrow[tid + 256 * i];

  __shared__ int wcnt[4];
  __shared__ int lcnt;

  unsigned lo = 0u, hi = 0x7F80u;   // bf16 bits; za >= 0 -> order-preserving
  for (int it = 0; it < 15; ++it) { // full resolution: lo = exact 32nd-largest bf16 value
    unsigned mid = (lo + hi) >> 1;
    int c = 0;
#pragma unroll
    for (int i = 0; i < 8; ++i) {
      const unsigned* p = (const unsigned*)&v[i];
#pragma unroll
      for (int e = 0; e < 4; ++e) {
        unsigned u = p[e];
        c += ((u & 0xFFFFu) >= mid) ? 1 : 0;
        c += ((u >> 16) >= mid) ? 1 : 0;
      }
    }
#pragma unroll
    for (int off = 32; off; off >>= 1) c += __shfl_xor(c, off, 64);
    if ((tid & 63) == 0) wcnt[tid >> 6] = c;
    __syncthreads();
    int tot = wcnt[0] + wcnt[1] + wcnt[2] + wcnt[3];
    __syncthreads();
    if (tot >= NK) lo = mid; else hi = mid;
  }

  float thr = __uint_as_float(lo << 16) - DELTA;
  if (thr < 1e-12f) thr = 1e-12f;   // degenerate rows: strict positives only
  if (tid == 0) lcnt = 0;
  __syncthreads();
#pragma unroll
  for (int i = 0; i < 8; ++i) {
    const unsigned* p = (const unsigned*)&v[i];
#pragma unroll
    for (int e = 0; e < 4; ++e) {
      unsigned u = p[e];
      int hbase = (tid + 256 * i) * 8 + e * 2;
      float f0 = __uint_as_float((u & 0xFFFFu) << 16);
      float f1 = __uint_as_float(u & 0xFFFF0000u);
      if (f0 >= thr) { int s = atomicAdd(&lcnt, 1); if (s < CAND_MAX) cand_idx[(size_t)b * CAND_MAX + s] = hbase; }
      if (f1 >= thr) { int s = atomicAdd(&lcnt, 1); if (s < CAND_MAX) cand_idx[(size_t)b * CAND_MAX + s] = hbase + 1; }
    }
  }
  __syncthreads();
  if (tid == 0) cand_cnt[b] = (lcnt < CAND_MAX) ? lcnt : CAND_MAX;
}

// ---------------- K5: exact recompute + top-32 + z write + sparse decode (fused) ----------------
__global__ __launch_bounds__(256) void finalize_kernel(
    const float* __restrict__ x, const float* __restrict__ W_enc,
    const float* __restrict__ b_enc,
    const int* __restrict__ cand_idx, const int* __restrict__ cand_cnt,
    const float* __restrict__ WdecT, const float* __restrict__ b_dec,
    float* __restrict__ zout, float* __restrict__ xhat) {
  int b = blockIdx.x, tid = threadIdx.x;
  int wid = tid >> 6, l = tid & 63;
  __shared__ __align__(16) float xr[ND];
  __shared__ float cv[CAND_MAX];
  __shared__ int   ci[CAND_MAX];
  __shared__ float sv[NK];
  __shared__ int   si[NK];

  int cnt = cand_cnt[b];
  {
    const float4* xrow = (const float4*)(x + (size_t)b * ND);
    for (int i = tid; i < ND / 4; i += 256) ((float4*)xr)[i] = xrow[i];
    for (int c = tid; c < cnt; c += 256) ci[c] = cand_idx[(size_t)b * CAND_MAX + c];
  }
  __syncthreads();

  // exact f32 dot per candidate (one wave each) — value depends only on h: order-independent
  for (int c = wid; c < cnt; c += 4) {
    int h = ci[c];
    const float* wrow = W_enc + (size_t)h * ND;
    float s = 0.f;
#pragma unroll
    for (int i = 0; i < 12; ++i) s = fmaf(wrow[l + 64 * i], xr[l + 64 * i], s);
#pragma unroll
    for (int off = 32; off; off >>= 1) s += __shfl_xor(s, off, 64);
    if (l == 0) cv[c] = fmaxf(s + b_enc[h], 0.f);
  }
  __syncthreads();

  // wave 0: deterministic top-32 by (value desc, index asc) — total order, set-deterministic
  if (wid == 0) {
    float lv[8]; int lh[8];
#pragma unroll
    for (int ii = 0; ii < 8; ++ii) {
      int c = l + 64 * ii;
      if (c < cnt) { lv[ii] = cv[c]; lh[ii] = ci[c]; }
      else         { lv[ii] = -1.f;  lh[ii] = 0x7fffffff; }
    }
    for (int r = 0; r < NK; ++r) {
      float bv = -1.f; int bh = 0x7fffffff; int bl = l; int bii = 0;
#pragma unroll
      for (int ii = 0; ii < 8; ++ii)
        if (lv[ii] > bv || (lv[ii] == bv && lh[ii] < bh)) { bv = lv[ii]; bh = lh[ii]; bii = ii; }
#pragma unroll
      for (int off = 32; off; off >>= 1) {
        float ov = __shfl_xor(bv, off, 64);
        int   oh = __shfl_xor(bh, off, 64);
        int   ol = __shfl_xor(bl, off, 64);
        int   oi = __shfl_xor(bii, off, 64);
        if (ov > bv || (ov == bv && oh < bh)) { bv = ov; bh = oh; bl = ol; bii = oi; }
      }
      if (l == 0) {
        if (bv > -0.5f) { sv[r] = bv; si[r] = bh; }
        else            { sv[r] = 0.f; si[r] = -1; }   // sentinel: no write collision
      }
#pragma unroll
      for (int ii = 0; ii < 8; ++ii)
        if (ii == bii && l == bl && bv > -0.5f) lv[ii] = -1.f;  // retire winner
    }
  }
  __syncthreads();

  // z row: zero-fill f32, scatter exact top-32 (guarded: padding never writes)
  float4 z4 = make_float4(0.f, 0.f, 0.f, 0.f);
  float4* zr = (float4*)(zout + (size_t)b * NH);
  for (int i = tid; i < NH / 4; i += 256) zr[i] = z4;
  __syncthreads();
  if (tid < NK) {
    int s = si[tid];
    if (s >= 0) zout[(size_t)b * NH + s] = sv[tid];
  }

  // sparse decode: xhat[b,:] = b_dec + sum_j sv[j] * WdecT[si[j],:]  (sv=0 for padding)
  float a0 = b_dec[tid], a1 = b_dec[tid + 256], a2 = b_dec[tid + 512];
#pragma unroll 8
  for (int j = 0; j < NK; ++j) {
    int hj = si[j]; hj = (hj < 0) ? 0 : hj;
    const float* wrow = WdecT + (size_t)hj * ND;
    float vj = sv[j];
    a0 = fmaf(vj, wrow[tid],       a0);
    a1 = fmaf(vj, wrow[tid + 256], a1);
    a2 = fmaf(vj, wrow[tid + 512], a2);
  }
  xhat[(size_t)b * ND + tid]       = a0;
  xhat[(size_t)b * ND + tid + 256] = a1;
  xhat[(size_t)b * ND + tid + 512] = a2;
}

// ---------------- launcher ----------------
extern "C" void kernel_launch(void* const* d_in, const int* in_sizes, int n_in,
                              void* d_out, int out_size, void* d_ws, size_t ws_size,
                              hipStream_t stream) {
  const float* x     = (const float*)d_in[0];
  const float* W_enc = (const float*)d_in[1];
  const float* b_enc = (const float*)d_in[2];
  const float* W_dec = (const float*)d_in[3];
  const float* b_dec = (const float*)d_in[4];

  float* xhat = (float*)d_out;
  float* zout = (float*)d_out + (size_t)NB * ND;       // final z (f32)
  unsigned short* za = (unsigned short*)zout;          // approx z (bf16) reuses z region

  char* ws = (char*)d_ws;
  unsigned short* x_bf    = (unsigned short*)(ws + OFF_XBF);
  unsigned short* wenc_bf = (unsigned short*)(ws + OFF_WENCB);
  float*          wdecT   = (float*)(ws + OFF_WDECT);
  int*            cidx    = (int*)(ws + OFF_CIDX);
  int*            ccnt    = (int*)(ws + OFF_CCNT);

  cast_bf16_kernel<<<1024, 256, 0, stream>>>(x, x_bf, NB * ND / 4);
  cast_bf16_kernel<<<2048, 256, 0, stream>>>(W_enc, wenc_bf, NH * ND / 4);
  transpose_kernel<<<dim3(NH / 32, ND / 32), dim3(32, 8), 0, stream>>>(W_dec, wdecT);
  encode_gemm_kernel<<<(NB / 128) * (NH / 128), 256, 0, stream>>>(x_bf, wenc_bf, b_enc, za);
  select_kernel<<<NB, 256, 0, stream>>>(za, cidx, ccnt);
  finalize_kernel<<<NB, 256, 0, stream>>>(x, W_enc, b_enc, cidx, ccnt, wdecT, b_dec, zout, xhat);
}